// Round 1
// baseline (263.167 us; speedup 1.0000x reference)
//
#include <hip/hip_runtime.h>
#include <hip/hip_bf16.h>
#include <hip/hip_cooperative_groups.h>

#define N_NODES 50000
#define N_EDGES 800000
#define DIM 96
#define NPART 256                 // partitions of 196 target nodes
#define PSZ 196                   // nodes per partition
#define NBINBLK 196               // edge-binning virtual blocks (4096 edges each)
#define BINCAP 48                 // slots per (partition, bin-block) cell; mean 16, +8 sigma
#define BPP (NBINBLK * BINCAP)    // 9408 slots per partition
#define CAP 4096                  // recs/ssrc buffer (mean 3125, sigma 56 -> +17 sigma)

typedef unsigned int uint;
typedef unsigned short u16;
using u16x8 = __attribute__((ext_vector_type(8))) unsigned short;

__device__ __forceinline__ u16 f2bf(float f) {
    __hip_bfloat16 h = __float2bfloat16(f);
    return *reinterpret_cast<u16*>(&h);
}
__device__ __forceinline__ float bf2f(u16 u) {
    return __uint_as_float(((uint)u) << 16);
}
// exact floor(t/196) for t < 50000
__device__ __forceinline__ int pdiv(int t) { return (int)(((uint)t * 85599u) >> 24); }

// ---------------------------------------------------------------------------
// One-wave inclusive scan of a 256-int LDS array (wave 0 only; caller must
// __syncthreads() before and after).
// ---------------------------------------------------------------------------
__device__ __forceinline__ void wave_scan256(int* a, int tid) {
    if (tid < 64) {
        int v0 = a[tid * 4], v1 = a[tid * 4 + 1], v2 = a[tid * 4 + 2], v3 = a[tid * 4 + 3];
        int s01 = v0 + v1;
        int s = s01 + v2 + v3;
        int inc = s;
#pragma unroll
        for (int off = 1; off < 64; off <<= 1) {
            int n = __shfl_up(inc, off, 64);
            if (tid >= off) inc += n;
        }
        int base = inc - s;
        a[tid * 4]     = base + v0;
        a[tid * 4 + 1] = base + s01;
        a[tid * 4 + 2] = base + s01 + v2;
        a[tid * 4 + 3] = base + s;
    }
}

// ---------------------------------------------------------------------------
// Single cooperative persistent kernel: 256 blocks x 1024 threads, 1 block/CU
// (LDS union = 150 KB). Phase A: bin edges (blocks < 196) + pack x -> bf16
// (all blocks). grid.sync(). Phase B: per-partition sort/gather/mean/MFMA
// (identical phase logic to the previous fused_k).
// ---------------------------------------------------------------------------
__global__ __launch_bounds__(1024) void fused_all(
    const float* __restrict__ x, const int* __restrict__ ei,
    u16* __restrict__ xbf, uint* __restrict__ part_edges, int* __restrict__ counts,
    const float* __restrict__ Wself, const float* __restrict__ bself,
    const float* __restrict__ Wneigh, const float* __restrict__ bneigh,
    float* __restrict__ out)
{
    using short8 = __attribute__((ext_vector_type(8))) short;
    using f32x4  = __attribute__((ext_vector_type(4))) float;

    __shared__ __align__(16) union {
        struct {                          // Phase A (binning): 50176 B
            uint bins[NPART * BINCAP];    // 49152 B
            int  bcnt[NPART];             //  1024 B
        } a;
        struct {                          // Phase B (partition): 150272 B
            u16   Axm[208 * 200];         // 83200 B
            short Bb[96 * 200];           // 38400 B
            uint  recs[CAP];              // 16384 B
            u16   ssrc[CAP];              //  8192 B
            int   bc[256];
            int   csc[256];
            int   hist[256];
            int   cur[256];
        } b;
    } sm;

    const int tid = threadIdx.x;
    const int p = blockIdx.x;

    // ================= Phase A1: bin 4096 contiguous edges (blocks < 196) ====
    // NOTE: 196*4096 = 802816 > N_EDGES — tail guard is load-bearing.
    if (p < NBINBLK) {
        if (tid < NPART) sm.a.bcnt[tid] = 0;
        __syncthreads();

        const int e0 = p * 4096 + tid * 4;
        if (e0 + 4 <= N_EDGES) {
            int4 s4 = *reinterpret_cast<const int4*>(ei + e0);
            int4 t4 = *reinterpret_cast<const int4*>(ei + N_EDGES + e0);
            int ss[4] = {s4.x, s4.y, s4.z, s4.w};
            int tt[4] = {t4.x, t4.y, t4.z, t4.w};
#pragma unroll
            for (int k = 0; k < 4; k++) {
                int pp = pdiv(tt[k]);
                int local = tt[k] - pp * PSZ;
                int slot = atomicAdd(&sm.a.bcnt[pp], 1);
                if (slot < BINCAP)
                    sm.a.bins[pp * BINCAP + slot] = ((uint)local << 16) | (uint)ss[k];
            }
        } else {
            for (int j = 0; j < 4; j++) {
                int e = e0 + j;
                if (e < N_EDGES) {
                    int sv = ei[e];
                    int tv = ei[N_EDGES + e];
                    int pp = pdiv(tv);
                    int local = tv - pp * PSZ;
                    int slot = atomicAdd(&sm.a.bcnt[pp], 1);
                    if (slot < BINCAP)
                        sm.a.bins[pp * BINCAP + slot] = ((uint)local << 16) | (uint)sv;
                }
            }
        }
        __syncthreads();

        if (tid < NPART)
            counts[tid * NBINBLK + p] = min(sm.a.bcnt[tid], BINCAP);

        for (int i = tid; i < NPART * BINCAP; i += 1024) {
            int pc = i / BINCAP;
            int s = i - pc * BINCAP;
            if (s < sm.a.bcnt[pc])
                part_edges[(size_t)pc * BPP + p * BINCAP + s] = sm.a.bins[i];
        }
    }

    // ================= Phase A2: pack x f32 -> bf16 (all blocks) =============
    {
        const int gid = p * 1024 + tid;
        for (int i4 = gid; i4 < (N_NODES * DIM) / 4; i4 += NPART * 1024) {
            float4 v = *reinterpret_cast<const float4*>(x + i4 * 4);
            ushort4 o;
            o.x = f2bf(v.x); o.y = f2bf(v.y); o.z = f2bf(v.z); o.w = f2bf(v.w);
            *reinterpret_cast<ushort4*>(xbf + i4 * 4) = o;
        }
    }

    __threadfence();
    cooperative_groups::this_grid().sync();

    // ================= Phase B: per-partition (one block per partition) ======
    const int node0 = p * PSZ;

    // ---- Bb from global ----
    for (int idx = tid; idx < 96 * 96; idx += 1024) {
        int j = idx / 96;
        int k = idx - j * 96;
        sm.b.Bb[j * 200 + k]      = (short)f2bf(Wself[idx]);
        sm.b.Bb[j * 200 + 96 + k] = (short)f2bf(Wneigh[idx]);
    }

    // ---- counts row (coalesced) + init ----
    if (tid < 256) {
        int v = (tid < NBINBLK) ? counts[p * NBINBLK + tid] : 0;
        sm.b.bc[tid] = v;
        sm.b.csc[tid] = v;
        sm.b.cur[tid] = 0;
    }

    // ---- stage x-half of Axm ----
    for (int i = tid; i < PSZ * 12; i += 1024) {
        int n = i / 12, t = i - n * 12;
        int node = node0 + n;
        short8 v = (short8)0;
        if (node < N_NODES)
            v = *reinterpret_cast<const short8*>(xbf + (size_t)node * DIM + t * 8);
        *reinterpret_cast<short8*>(&sm.b.Axm[n * 200 + t * 8]) = v;
    }
    __syncthreads();

    wave_scan256(sm.b.csc, tid);
    __syncthreads();
    int m = sm.b.csc[255]; if (m > CAP) m = CAP;

    // ---- compact cells -> recs ----
    for (int i = tid; i < NBINBLK * BINCAP; i += 1024) {
        int b = i / BINCAP;
        int s = i - b * BINCAP;
        if (s < sm.b.bc[b]) {
            int dst = sm.b.csc[b] - sm.b.bc[b] + s;
            if (dst < CAP)
                sm.b.recs[dst] = part_edges[(size_t)p * BPP + i];
        }
    }
    __syncthreads();

    // ---- node histogram + scan ----
    for (int i = tid; i < m; i += 1024)
        atomicAdd(&sm.b.cur[sm.b.recs[i] >> 16], 1);
    __syncthreads();
    if (tid < 256) sm.b.hist[tid] = sm.b.cur[tid];
    __syncthreads();
    wave_scan256(sm.b.hist, tid);
    __syncthreads();
    if (tid < 256) sm.b.cur[tid] = sm.b.hist[tid] - sm.b.cur[tid];
    __syncthreads();

    // ---- scatter to node-sorted ssrc ----
    for (int i = tid; i < m; i += 1024) {
        uint r = sm.b.recs[i];
        int pos = atomicAdd(&sm.b.cur[r >> 16], 1);
        sm.b.ssrc[pos] = (u16)(r & 0xFFFF);
    }
    __syncthreads();

    // ---- gather + mean -> Axm[.. + 96]: 85 groups of 12 lanes, 16B/lane ----
    if (tid < 1020) {
        const int g = tid / 12;
        const int l = tid - g * 12;
        const int l8 = l * 8;
        for (int r = g; r < PSZ; r += 85) {
            int end = sm.b.hist[r];
            int beg = (r > 0) ? sm.b.hist[r - 1] : 0;
            float a0 = 0.f, a1 = 0.f, a2 = 0.f, a3 = 0.f;
            float a4 = 0.f, a5 = 0.f, a6 = 0.f, a7 = 0.f;
            int i = beg;
            for (; i + 3 < end; i += 4) {
                int s0 = sm.b.ssrc[i], s1 = sm.b.ssrc[i + 1];
                int s2 = sm.b.ssrc[i + 2], s3 = sm.b.ssrc[i + 3];
                u16x8 v0 = *reinterpret_cast<const u16x8*>(xbf + (size_t)s0 * DIM + l8);
                u16x8 v1 = *reinterpret_cast<const u16x8*>(xbf + (size_t)s1 * DIM + l8);
                u16x8 v2 = *reinterpret_cast<const u16x8*>(xbf + (size_t)s2 * DIM + l8);
                u16x8 v3 = *reinterpret_cast<const u16x8*>(xbf + (size_t)s3 * DIM + l8);
                a0 += bf2f(v0[0]) + bf2f(v1[0]) + bf2f(v2[0]) + bf2f(v3[0]);
                a1 += bf2f(v0[1]) + bf2f(v1[1]) + bf2f(v2[1]) + bf2f(v3[1]);
                a2 += bf2f(v0[2]) + bf2f(v1[2]) + bf2f(v2[2]) + bf2f(v3[2]);
                a3 += bf2f(v0[3]) + bf2f(v1[3]) + bf2f(v2[3]) + bf2f(v3[3]);
                a4 += bf2f(v0[4]) + bf2f(v1[4]) + bf2f(v2[4]) + bf2f(v3[4]);
                a5 += bf2f(v0[5]) + bf2f(v1[5]) + bf2f(v2[5]) + bf2f(v3[5]);
                a6 += bf2f(v0[6]) + bf2f(v1[6]) + bf2f(v2[6]) + bf2f(v3[6]);
                a7 += bf2f(v0[7]) + bf2f(v1[7]) + bf2f(v2[7]) + bf2f(v3[7]);
            }
            for (; i < end; i++) {
                int s = sm.b.ssrc[i];
                u16x8 v = *reinterpret_cast<const u16x8*>(xbf + (size_t)s * DIM + l8);
                a0 += bf2f(v[0]); a1 += bf2f(v[1]); a2 += bf2f(v[2]); a3 += bf2f(v[3]);
                a4 += bf2f(v[4]); a5 += bf2f(v[5]); a6 += bf2f(v[6]); a7 += bf2f(v[7]);
            }
            float inv = (end > beg) ? 1.0f / (float)(end - beg) : 0.f;
            u16x8 o;
            o[0] = f2bf(a0 * inv); o[1] = f2bf(a1 * inv);
            o[2] = f2bf(a2 * inv); o[3] = f2bf(a3 * inv);
            o[4] = f2bf(a4 * inv); o[5] = f2bf(a5 * inv);
            o[6] = f2bf(a6 * inv); o[7] = f2bf(a7 * inv);
            *reinterpret_cast<u16x8*>(&sm.b.Axm[r * 200 + 96 + l8]) = o;
        }
    }
    __syncthreads();

    // ---- MFMA: 13 row-tiles of 16 over waves 0..12 ----
    const int wave = tid >> 6;
    const int lane = tid & 63;
    const int quad = lane >> 4;
    const int m16  = lane & 15;

    if (wave < 13) {
        const int rloc = wave * 16;
        f32x4 acc[6];
#pragma unroll
        for (int nt = 0; nt < 6; nt++) acc[nt] = (f32x4){0.f, 0.f, 0.f, 0.f};

#pragma unroll
        for (int kt = 0; kt < 6; kt++) {
            short8 a = *reinterpret_cast<const short8*>(
                &sm.b.Axm[(rloc + m16) * 200 + kt * 32 + quad * 8]);
#pragma unroll
            for (int nt = 0; nt < 6; nt++) {
                short8 b = *reinterpret_cast<const short8*>(
                    &sm.b.Bb[(nt * 16 + m16) * 200 + kt * 32 + quad * 8]);
                acc[nt] = __builtin_amdgcn_mfma_f32_16x16x32_bf16(a, b, acc[nt], 0, 0, 0);
            }
        }

#pragma unroll
        for (int nt = 0; nt < 6; nt++) {
            int col = nt * 16 + m16;
            float bias = bself[col] + bneigh[col];
#pragma unroll
            for (int reg = 0; reg < 4; reg++) {
                int rl = rloc + quad * 4 + reg;
                int row = node0 + rl;
                if (rl < PSZ && row < N_NODES)
                    out[(size_t)row * DIM + col] = acc[nt][reg] + bias;
            }
        }
    }
}

extern "C" void kernel_launch(void* const* d_in, const int* in_sizes, int n_in,
                              void* d_out, int out_size, void* d_ws, size_t ws_size,
                              hipStream_t stream) {
    const float* x      = (const float*)d_in[0];
    const int*   ei     = (const int*)d_in[1];
    const float* Wself  = (const float*)d_in[2];
    const float* bself  = (const float*)d_in[3];
    const float* Wneigh = (const float*)d_in[4];
    const float* bneigh = (const float*)d_in[5];
    float* out = (float*)d_out;

    // Workspace (fully written before read; no memset):
    uint* part_edges = (uint*)d_ws;                                 // 256*9408*4 = 9.63 MB
    int*  counts     = (int*)(part_edges + (size_t)NPART * BPP);    // 256*196*4 = 200 KB
    u16*  xbf        = (u16*)(counts + NPART * NBINBLK);            // 9.6 MB

    void* kargs[] = { (void*)&x, (void*)&ei, (void*)&xbf, (void*)&part_edges,
                      (void*)&counts, (void*)&Wself, (void*)&bself,
                      (void*)&Wneigh, (void*)&bneigh, (void*)&out };
    hipLaunchCooperativeKernel((void*)fused_all, dim3(NPART), dim3(1024),
                               kargs, 0, stream);
}

// Round 2
// 123.981 us; speedup vs baseline: 2.1226x; 2.1226x over previous
//
#include <hip/hip_runtime.h>
#include <hip/hip_bf16.h>

#define N_NODES 50000
#define N_EDGES 800000
#define DIM 96
#define NPART 256                 // partitions of 196 target nodes
#define PSZ 196                   // nodes per partition
#define NBINBLK 196               // edge-binning blocks (4096 edges each)
#define BINCAP 48                 // slots per (partition, bin-block) cell; mean 16, +8 sigma
#define BPP (NBINBLK * BINCAP)    // 9408 slots per partition
#define CAP 4096                  // recs/ssrc buffer (mean 3125, sigma 56 -> +17 sigma)
#define NPACK_BLOCKS 4688         // ceil(4.8M elems / (256*4))

typedef unsigned int uint;
typedef unsigned short u16;
using u16x8 = __attribute__((ext_vector_type(8))) unsigned short;

__device__ __forceinline__ u16 f2bf(float f) {
    __hip_bfloat16 h = __float2bfloat16(f);
    return *reinterpret_cast<u16*>(&h);
}
__device__ __forceinline__ float bf2f(u16 u) {
    return __uint_as_float(((uint)u) << 16);
}
// exact floor(t/196) for t < 50000 (overestimate < 0.003 << 1/196 slack)
__device__ __forceinline__ int pdiv(int t) { return (int)(((uint)t * 85599u) >> 24); }

// ---------------------------------------------------------------------------
// K1: blocks [0,196): bin 4096 contiguous edges into fixed per-(p,b) cells.
//     blocks [196,...): pack x f32 -> bf16.
// NOTE: 196*4096 = 802816 > N_EDGES — the tail guard is load-bearing
// (round-10 dropped it and binned 2816 phantom edges -> absmax 0.40).
// NOTE (round-1): cooperative single-kernel fusion of K1+K2 regressed 123->263us
// (grid.sync machinery ~150us of stall at 1 block/CU). Keep two launches.
// ---------------------------------------------------------------------------
__global__ __launch_bounds__(256) void packbin_k(
    const float* __restrict__ x, const int* __restrict__ ei,
    u16* __restrict__ xbf, uint* __restrict__ part_edges,
    int* __restrict__ counts)
{
    __shared__ uint bins[NPART * BINCAP];   // 49152 B
    __shared__ int  bcnt[NPART];
    const int tid = threadIdx.x;

    if (blockIdx.x >= NBINBLK) {
        int pb = blockIdx.x - NBINBLK;
        int i4 = (pb * 256 + tid) * 4;
        if (i4 < N_NODES * DIM) {
            float4 v = *reinterpret_cast<const float4*>(x + i4);
            ushort4 o;
            o.x = f2bf(v.x); o.y = f2bf(v.y); o.z = f2bf(v.z); o.w = f2bf(v.w);
            *reinterpret_cast<ushort4*>(xbf + i4) = o;
        }
        return;
    }

    for (int i = tid; i < NPART; i += 256) bcnt[i] = 0;
    __syncthreads();

    const int e0 = blockIdx.x * 4096 + tid * 16;
    if (e0 + 16 <= N_EDGES) {
#pragma unroll
        for (int j = 0; j < 4; j++) {
            int4 s = *reinterpret_cast<const int4*>(ei + e0 + j * 4);
            int4 t = *reinterpret_cast<const int4*>(ei + N_EDGES + e0 + j * 4);
            int ss[4] = {s.x, s.y, s.z, s.w};
            int tt[4] = {t.x, t.y, t.z, t.w};
#pragma unroll
            for (int k = 0; k < 4; k++) {
                int p = pdiv(tt[k]);
                int local = tt[k] - p * PSZ;
                int slot = atomicAdd(&bcnt[p], 1);
                if (slot < BINCAP)
                    bins[p * BINCAP + slot] = ((uint)local << 16) | (uint)ss[k];
            }
        }
    } else {
        for (int j = 0; j < 16; j++) {
            int e = e0 + j;
            if (e < N_EDGES) {
                int sv = ei[e];
                int tv = ei[N_EDGES + e];
                int p = pdiv(tv);
                int local = tv - p * PSZ;
                int slot = atomicAdd(&bcnt[p], 1);
                if (slot < BINCAP)
                    bins[p * BINCAP + slot] = ((uint)local << 16) | (uint)sv;
            }
        }
    }
    __syncthreads();

    for (int p = tid; p < NPART; p += 256)
        counts[p * NBINBLK + blockIdx.x] = min(bcnt[p], BINCAP);

    for (int i = tid; i < NPART * BINCAP; i += 256) {
        int p = i / BINCAP;
        int s = i - p * BINCAP;
        if (s < bcnt[p])
            part_edges[(size_t)p * BPP + blockIdx.x * BINCAP + s] = bins[i];
    }
}

// ---------------------------------------------------------------------------
// One-wave inclusive scan of a 256-int LDS array (wave 0 only; caller must
// __syncthreads() before and after). 4 elems/lane + shfl_up wave scan.
// ---------------------------------------------------------------------------
__device__ __forceinline__ void wave_scan256(int* a, int tid) {
    if (tid < 64) {
        int v0 = a[tid * 4], v1 = a[tid * 4 + 1], v2 = a[tid * 4 + 2], v3 = a[tid * 4 + 3];
        int s01 = v0 + v1;
        int s = s01 + v2 + v3;              // chunk sum
        int inc = s;
#pragma unroll
        for (int off = 1; off < 64; off <<= 1) {
            int n = __shfl_up(inc, off, 64);
            if (tid >= off) inc += n;
        }
        int base = inc - s;                  // exclusive prefix of chunk
        a[tid * 4]     = base + v0;
        a[tid * 4 + 1] = base + s01;
        a[tid * 4 + 2] = base + s01 + v2;
        a[tid * 4 + 3] = base + s;           // = inc
    }
}

// ---------------------------------------------------------------------------
// K2: one block per partition (196 nodes), 1024 threads, 256 blocks.
// counts scan -> compact recs -> node hist/sort -> 12-lane x 16B gather
// (85 groups, unroll x8 => ~680 row-loads in flight/CU) -> mean -> MFMA.
// Gather is LATENCY-bound (dependent L2/L3 round trips per group), so the
// unroll depth is the lever; VGPRs are free (52 used of ~512/wave at 16 waves).
// ---------------------------------------------------------------------------
__global__ __launch_bounds__(1024) void fused_k(
    const u16* __restrict__ xbf,
    const uint* __restrict__ part_edges,
    const int* __restrict__ counts,
    const float* __restrict__ Wself, const float* __restrict__ bself,
    const float* __restrict__ Wneigh, const float* __restrict__ bneigh,
    float* __restrict__ out)
{
    using short8 = __attribute__((ext_vector_type(8))) short;
    using f32x4  = __attribute__((ext_vector_type(4))) float;

    __shared__ u16   Axm[208 * 200];     // 83200 B
    __shared__ short Bb[96 * 200];       // 38400 B
    __shared__ uint  recs[CAP];          // 16384 B
    __shared__ u16   ssrc[CAP];          //  8192 B
    __shared__ int   bc[256];
    __shared__ int   csc[256];
    __shared__ int   hist[256];
    __shared__ int   cur[256];

    const int tid = threadIdx.x;
    const int p = blockIdx.x;
    const int node0 = p * PSZ;

    // ---- Bb from global (independent; overlaps sort setup) ----
    for (int idx = tid; idx < 96 * 96; idx += 1024) {
        int j = idx / 96;
        int k = idx - j * 96;
        Bb[j * 200 + k]      = (short)f2bf(Wself[idx]);
        Bb[j * 200 + 96 + k] = (short)f2bf(Wneigh[idx]);
    }

    // ---- counts row (coalesced) + init ----
    if (tid < 256) {
        int v = (tid < NBINBLK) ? counts[p * NBINBLK + tid] : 0;
        bc[tid] = v;
        csc[tid] = v;
        cur[tid] = 0;
    }

    // ---- stage x-half of Axm ----
    for (int i = tid; i < PSZ * 12; i += 1024) {
        int n = i / 12, t = i - n * 12;
        int node = node0 + n;
        short8 v = (short8)0;
        if (node < N_NODES)
            v = *reinterpret_cast<const short8*>(xbf + (size_t)node * DIM + t * 8);
        *reinterpret_cast<short8*>(&Axm[n * 200 + t * 8]) = v;
    }
    __syncthreads();

    wave_scan256(csc, tid);
    __syncthreads();
    int m = csc[255]; if (m > CAP) m = CAP;

    // ---- compact cells -> recs ----
    for (int i = tid; i < NBINBLK * BINCAP; i += 1024) {
        int b = i / BINCAP;
        int s = i - b * BINCAP;
        if (s < bc[b]) {
            int dst = csc[b] - bc[b] + s;
            if (dst < CAP)
                recs[dst] = part_edges[(size_t)p * BPP + i];
        }
    }
    __syncthreads();

    // ---- node histogram + scan ----
    for (int i = tid; i < m; i += 1024)
        atomicAdd(&cur[recs[i] >> 16], 1);
    __syncthreads();
    if (tid < 256) hist[tid] = cur[tid];
    __syncthreads();
    wave_scan256(hist, tid);
    __syncthreads();
    if (tid < 256) cur[tid] = hist[tid] - cur[tid];   // exclusive cursor
    __syncthreads();

    // ---- scatter to node-sorted ssrc ----
    for (int i = tid; i < m; i += 1024) {
        uint r = recs[i];
        int pos = atomicAdd(&cur[r >> 16], 1);
        ssrc[pos] = (u16)(r & 0xFFFF);
    }
    __syncthreads();

    // ---- gather + mean -> Axm[.. + 96]: 85 groups of 12 lanes, 16B/lane ----
    if (tid < 1020) {
        const int g = tid / 12;
        const int l = tid - g * 12;
        const int l8 = l * 8;                 // u16 offset in row
        for (int r = g; r < PSZ; r += 85) {
            int end = hist[r];
            int beg = (r > 0) ? hist[r - 1] : 0;
            float a0 = 0.f, a1 = 0.f, a2 = 0.f, a3 = 0.f;
            float a4 = 0.f, a5 = 0.f, a6 = 0.f, a7 = 0.f;
            int i = beg;
            // 8-deep: halve the number of dependent latency chunks vs 4-deep
            for (; i + 7 < end; i += 8) {
                int s0 = ssrc[i],     s1 = ssrc[i + 1], s2 = ssrc[i + 2], s3 = ssrc[i + 3];
                int s4 = ssrc[i + 4], s5 = ssrc[i + 5], s6 = ssrc[i + 6], s7 = ssrc[i + 7];
                u16x8 v0 = *reinterpret_cast<const u16x8*>(xbf + (size_t)s0 * DIM + l8);
                u16x8 v1 = *reinterpret_cast<const u16x8*>(xbf + (size_t)s1 * DIM + l8);
                u16x8 v2 = *reinterpret_cast<const u16x8*>(xbf + (size_t)s2 * DIM + l8);
                u16x8 v3 = *reinterpret_cast<const u16x8*>(xbf + (size_t)s3 * DIM + l8);
                u16x8 v4 = *reinterpret_cast<const u16x8*>(xbf + (size_t)s4 * DIM + l8);
                u16x8 v5 = *reinterpret_cast<const u16x8*>(xbf + (size_t)s5 * DIM + l8);
                u16x8 v6 = *reinterpret_cast<const u16x8*>(xbf + (size_t)s6 * DIM + l8);
                u16x8 v7 = *reinterpret_cast<const u16x8*>(xbf + (size_t)s7 * DIM + l8);
                a0 += bf2f(v0[0]) + bf2f(v1[0]) + bf2f(v2[0]) + bf2f(v3[0])
                    + bf2f(v4[0]) + bf2f(v5[0]) + bf2f(v6[0]) + bf2f(v7[0]);
                a1 += bf2f(v0[1]) + bf2f(v1[1]) + bf2f(v2[1]) + bf2f(v3[1])
                    + bf2f(v4[1]) + bf2f(v5[1]) + bf2f(v6[1]) + bf2f(v7[1]);
                a2 += bf2f(v0[2]) + bf2f(v1[2]) + bf2f(v2[2]) + bf2f(v3[2])
                    + bf2f(v4[2]) + bf2f(v5[2]) + bf2f(v6[2]) + bf2f(v7[2]);
                a3 += bf2f(v0[3]) + bf2f(v1[3]) + bf2f(v2[3]) + bf2f(v3[3])
                    + bf2f(v4[3]) + bf2f(v5[3]) + bf2f(v6[3]) + bf2f(v7[3]);
                a4 += bf2f(v0[4]) + bf2f(v1[4]) + bf2f(v2[4]) + bf2f(v3[4])
                    + bf2f(v4[4]) + bf2f(v5[4]) + bf2f(v6[4]) + bf2f(v7[4]);
                a5 += bf2f(v0[5]) + bf2f(v1[5]) + bf2f(v2[5]) + bf2f(v3[5])
                    + bf2f(v4[5]) + bf2f(v5[5]) + bf2f(v6[5]) + bf2f(v7[5]);
                a6 += bf2f(v0[6]) + bf2f(v1[6]) + bf2f(v2[6]) + bf2f(v3[6])
                    + bf2f(v4[6]) + bf2f(v5[6]) + bf2f(v6[6]) + bf2f(v7[6]);
                a7 += bf2f(v0[7]) + bf2f(v1[7]) + bf2f(v2[7]) + bf2f(v3[7])
                    + bf2f(v4[7]) + bf2f(v5[7]) + bf2f(v6[7]) + bf2f(v7[7]);
            }
            for (; i + 3 < end; i += 4) {
                int s0 = ssrc[i], s1 = ssrc[i + 1], s2 = ssrc[i + 2], s3 = ssrc[i + 3];
                u16x8 v0 = *reinterpret_cast<const u16x8*>(xbf + (size_t)s0 * DIM + l8);
                u16x8 v1 = *reinterpret_cast<const u16x8*>(xbf + (size_t)s1 * DIM + l8);
                u16x8 v2 = *reinterpret_cast<const u16x8*>(xbf + (size_t)s2 * DIM + l8);
                u16x8 v3 = *reinterpret_cast<const u16x8*>(xbf + (size_t)s3 * DIM + l8);
                a0 += bf2f(v0[0]) + bf2f(v1[0]) + bf2f(v2[0]) + bf2f(v3[0]);
                a1 += bf2f(v0[1]) + bf2f(v1[1]) + bf2f(v2[1]) + bf2f(v3[1]);
                a2 += bf2f(v0[2]) + bf2f(v1[2]) + bf2f(v2[2]) + bf2f(v3[2]);
                a3 += bf2f(v0[3]) + bf2f(v1[3]) + bf2f(v2[3]) + bf2f(v3[3]);
                a4 += bf2f(v0[4]) + bf2f(v1[4]) + bf2f(v2[4]) + bf2f(v3[4]);
                a5 += bf2f(v0[5]) + bf2f(v1[5]) + bf2f(v2[5]) + bf2f(v3[5]);
                a6 += bf2f(v0[6]) + bf2f(v1[6]) + bf2f(v2[6]) + bf2f(v3[6]);
                a7 += bf2f(v0[7]) + bf2f(v1[7]) + bf2f(v2[7]) + bf2f(v3[7]);
            }
            for (; i < end; i++) {
                int s = ssrc[i];
                u16x8 v = *reinterpret_cast<const u16x8*>(xbf + (size_t)s * DIM + l8);
                a0 += bf2f(v[0]); a1 += bf2f(v[1]); a2 += bf2f(v[2]); a3 += bf2f(v[3]);
                a4 += bf2f(v[4]); a5 += bf2f(v[5]); a6 += bf2f(v[6]); a7 += bf2f(v[7]);
            }
            float inv = (end > beg) ? 1.0f / (float)(end - beg) : 0.f;
            u16x8 o;
            o[0] = f2bf(a0 * inv); o[1] = f2bf(a1 * inv);
            o[2] = f2bf(a2 * inv); o[3] = f2bf(a3 * inv);
            o[4] = f2bf(a4 * inv); o[5] = f2bf(a5 * inv);
            o[6] = f2bf(a6 * inv); o[7] = f2bf(a7 * inv);
            *reinterpret_cast<u16x8*>(&Axm[r * 200 + 96 + l8]) = o;
        }
    }
    __syncthreads();

    // ---- MFMA: 13 row-tiles of 16 over waves 0..12 ----
    const int wave = tid >> 6;
    const int lane = tid & 63;
    const int quad = lane >> 4;
    const int m16  = lane & 15;

    if (wave < 13) {
        const int rloc = wave * 16;
        f32x4 acc[6];
#pragma unroll
        for (int nt = 0; nt < 6; nt++) acc[nt] = (f32x4){0.f, 0.f, 0.f, 0.f};

#pragma unroll
        for (int kt = 0; kt < 6; kt++) {
            short8 a = *reinterpret_cast<const short8*>(
                &Axm[(rloc + m16) * 200 + kt * 32 + quad * 8]);
#pragma unroll
            for (int nt = 0; nt < 6; nt++) {
                short8 b = *reinterpret_cast<const short8*>(
                    &Bb[(nt * 16 + m16) * 200 + kt * 32 + quad * 8]);
                acc[nt] = __builtin_amdgcn_mfma_f32_16x16x32_bf16(a, b, acc[nt], 0, 0, 0);
            }
        }

#pragma unroll
        for (int nt = 0; nt < 6; nt++) {
            int col = nt * 16 + m16;
            float bias = bself[col] + bneigh[col];
#pragma unroll
            for (int reg = 0; reg < 4; reg++) {
                int rl = rloc + quad * 4 + reg;
                int row = node0 + rl;
                if (rl < PSZ && row < N_NODES)
                    out[(size_t)row * DIM + col] = acc[nt][reg] + bias;
            }
        }
    }
}

extern "C" void kernel_launch(void* const* d_in, const int* in_sizes, int n_in,
                              void* d_out, int out_size, void* d_ws, size_t ws_size,
                              hipStream_t stream) {
    const float* x      = (const float*)d_in[0];
    const int*   ei     = (const int*)d_in[1];
    const float* Wself  = (const float*)d_in[2];
    const float* bself  = (const float*)d_in[3];
    const float* Wneigh = (const float*)d_in[4];
    const float* bneigh = (const float*)d_in[5];
    float* out = (float*)d_out;

    // Workspace (fully written before read; no memset):
    uint* part_edges = (uint*)d_ws;                                 // 256*9408*4 = 9.63 MB
    int*  counts     = (int*)(part_edges + (size_t)NPART * BPP);    // 256*196*4 = 200 KB
    u16*  xbf        = (u16*)(counts + NPART * NBINBLK);            // 9.6 MB

    packbin_k<<<NBINBLK + NPACK_BLOCKS, 256, 0, stream>>>(
        x, ei, xbf, part_edges, counts);
    fused_k<<<NPART, 1024, 0, stream>>>(
        xbf, part_edges, counts, Wself, bself, Wneigh, bneigh, out);
}

// Round 3
// 122.490 us; speedup vs baseline: 2.1485x; 1.0122x over previous
//
#include <hip/hip_runtime.h>
#include <hip/hip_bf16.h>

#define N_NODES 50000
#define N_EDGES 800000
#define DIM 96
#define NPART 256                 // partitions of 196 target nodes
#define PSZ 196                   // nodes per partition
#define NBINBLK 196               // edge-binning blocks (4096 edges each)
#define BINCAP 48                 // slots per (partition, bin-block) cell; mean 16, +8 sigma
#define BPP (NBINBLK * BINCAP)    // 9408 slots per partition
#define CAP 4096                  // recs/ssrc buffer (mean 3125, sigma 56 -> +17 sigma)
#define NROWBLK 1563              // row-pack blocks: 32 rows/block, ceil(50000/32)

typedef unsigned int uint;
typedef unsigned short u16;

__device__ __forceinline__ u16 f2bf(float f) {
    __hip_bfloat16 h = __float2bfloat16(f);
    return *reinterpret_cast<u16*>(&h);
}
__device__ __forceinline__ float bf2f(u16 u) {
    return __uint_as_float(((uint)u) << 16);
}
// exact floor(t/196) for t < 50000 (overestimate < 0.003 << 1/196 slack)
__device__ __forceinline__ int pdiv(int t) { return (int)(((uint)t * 85599u) >> 24); }

// ---------------------------------------------------------------------------
// K1: blocks [0,196): bin 4096 contiguous edges into fixed per-(p,b) cells.
//     blocks [196,...): row-pack x -> bf16 row (self term) + int8 row with
//     per-row scale (gather term). 32 rows/block, 8 lanes/row, 12 elems/lane.
// NOTE: 196*4096 = 802816 > N_EDGES — the tail guard is load-bearing.
// NOTE (round-1): cooperative K1+K2 fusion regressed 123->263us (grid.sync
// stall ~150us at 1 block/CU). Keep two launches.
// NOTE (round-2): gather unroll 4->8 was neutral => gather is L2-fill/L3-BW
// bound (per-XCD compulsory ~9.6MB bf16), not latency-bound. Hence int8 rows:
// working set 9.6->4.8MB (~fits 4MiB per-XCD L2), gather bytes 153.6->76.8MB.
// ---------------------------------------------------------------------------
__global__ __launch_bounds__(256) void packbin_k(
    const float* __restrict__ x, const int* __restrict__ ei,
    u16* __restrict__ xbf, signed char* __restrict__ xq, float* __restrict__ scales,
    uint* __restrict__ part_edges, int* __restrict__ counts)
{
    __shared__ uint bins[NPART * BINCAP];   // 49152 B
    __shared__ int  bcnt[NPART];
    const int tid = threadIdx.x;

    if (blockIdx.x >= NBINBLK) {
        // ---- row-pack: 32 rows/block, 8 lanes/row, 12 elems/lane ----
        const int rb = blockIdx.x - NBINBLK;
        const int row = rb * 32 + (tid >> 3);
        if (row < N_NODES) {
            const int l = tid & 7;
            const float* rp = x + (size_t)row * DIM + l * 12;
            float4 f0 = *reinterpret_cast<const float4*>(rp);
            float4 f1 = *reinterpret_cast<const float4*>(rp + 4);
            float4 f2 = *reinterpret_cast<const float4*>(rp + 8);
            float v[12] = {f0.x, f0.y, f0.z, f0.w,
                           f1.x, f1.y, f1.z, f1.w,
                           f2.x, f2.y, f2.z, f2.w};
            float amax = 0.f;
#pragma unroll
            for (int k = 0; k < 12; k++) amax = fmaxf(amax, fabsf(v[k]));
#pragma unroll
            for (int mk = 1; mk < 8; mk <<= 1)
                amax = fmaxf(amax, __shfl_xor(amax, mk, 8));
            const float inv = (amax > 0.f) ? 127.0f / amax : 0.f;
            const float sc  = (amax > 0.f) ? amax * (1.0f / 127.0f) : 0.f;

            // bf16 row (self-term staging; unchanged precision)
            ushort4 h0, h1, h2;
            h0.x = f2bf(v[0]);  h0.y = f2bf(v[1]);  h0.z = f2bf(v[2]);  h0.w = f2bf(v[3]);
            h1.x = f2bf(v[4]);  h1.y = f2bf(v[5]);  h1.z = f2bf(v[6]);  h1.w = f2bf(v[7]);
            h2.x = f2bf(v[8]);  h2.y = f2bf(v[9]);  h2.z = f2bf(v[10]); h2.w = f2bf(v[11]);
            u16* hb = xbf + (size_t)row * DIM + l * 12;
            *reinterpret_cast<ushort4*>(hb)     = h0;
            *reinterpret_cast<ushort4*>(hb + 4) = h1;
            *reinterpret_cast<ushort4*>(hb + 8) = h2;

            // int8 row, round-to-nearest; |v|<=amax => |q|<=127, no clamp needed
            uint w[3];
#pragma unroll
            for (int g = 0; g < 3; g++) {
                int q0 = __float2int_rn(v[g * 4 + 0] * inv);
                int q1 = __float2int_rn(v[g * 4 + 1] * inv);
                int q2 = __float2int_rn(v[g * 4 + 2] * inv);
                int q3 = __float2int_rn(v[g * 4 + 3] * inv);
                w[g] = (uint)(q0 & 0xFF) | ((uint)(q1 & 0xFF) << 8) |
                       ((uint)(q2 & 0xFF) << 16) | ((uint)(q3 & 0xFF) << 24);
            }
            uint* qb = reinterpret_cast<uint*>(xq + (size_t)row * DIM) + l * 3;
            qb[0] = w[0]; qb[1] = w[1]; qb[2] = w[2];
            if (l == 0) scales[row] = sc;
        }
        return;
    }

    for (int i = tid; i < NPART; i += 256) bcnt[i] = 0;
    __syncthreads();

    const int e0 = blockIdx.x * 4096 + tid * 16;
    if (e0 + 16 <= N_EDGES) {
#pragma unroll
        for (int j = 0; j < 4; j++) {
            int4 s = *reinterpret_cast<const int4*>(ei + e0 + j * 4);
            int4 t = *reinterpret_cast<const int4*>(ei + N_EDGES + e0 + j * 4);
            int ss[4] = {s.x, s.y, s.z, s.w};
            int tt[4] = {t.x, t.y, t.z, t.w};
#pragma unroll
            for (int k = 0; k < 4; k++) {
                int p = pdiv(tt[k]);
                int local = tt[k] - p * PSZ;
                int slot = atomicAdd(&bcnt[p], 1);
                if (slot < BINCAP)
                    bins[p * BINCAP + slot] = ((uint)local << 16) | (uint)ss[k];
            }
        }
    } else {
        for (int j = 0; j < 16; j++) {
            int e = e0 + j;
            if (e < N_EDGES) {
                int sv = ei[e];
                int tv = ei[N_EDGES + e];
                int p = pdiv(tv);
                int local = tv - p * PSZ;
                int slot = atomicAdd(&bcnt[p], 1);
                if (slot < BINCAP)
                    bins[p * BINCAP + slot] = ((uint)local << 16) | (uint)sv;
            }
        }
    }
    __syncthreads();

    for (int p = tid; p < NPART; p += 256)
        counts[p * NBINBLK + blockIdx.x] = min(bcnt[p], BINCAP);

    for (int i = tid; i < NPART * BINCAP; i += 256) {
        int p = i / BINCAP;
        int s = i - p * BINCAP;
        if (s < bcnt[p])
            part_edges[(size_t)p * BPP + blockIdx.x * BINCAP + s] = bins[i];
    }
}

// ---------------------------------------------------------------------------
// One-wave inclusive scan of a 256-int LDS array (wave 0 only; caller must
// __syncthreads() before and after). 4 elems/lane + shfl_up wave scan.
// ---------------------------------------------------------------------------
__device__ __forceinline__ void wave_scan256(int* a, int tid) {
    if (tid < 64) {
        int v0 = a[tid * 4], v1 = a[tid * 4 + 1], v2 = a[tid * 4 + 2], v3 = a[tid * 4 + 3];
        int s01 = v0 + v1;
        int s = s01 + v2 + v3;              // chunk sum
        int inc = s;
#pragma unroll
        for (int off = 1; off < 64; off <<= 1) {
            int n = __shfl_up(inc, off, 64);
            if (tid >= off) inc += n;
        }
        int base = inc - s;                  // exclusive prefix of chunk
        a[tid * 4]     = base + v0;
        a[tid * 4 + 1] = base + s01;
        a[tid * 4 + 2] = base + s01 + v2;
        a[tid * 4 + 3] = base + s;           // = inc
    }
}

union QV { uint2 u; signed char b[8]; };

// ---------------------------------------------------------------------------
// K2: one block per partition (196 nodes), 1024 threads, 256 blocks.
// counts scan -> compact recs -> node hist/sort -> 12-lane x 8B int8 gather
// (dequant fma with per-row scale) -> mean -> MFMA.
// ---------------------------------------------------------------------------
__global__ __launch_bounds__(1024) void fused_k(
    const u16* __restrict__ xbf,
    const signed char* __restrict__ xq, const float* __restrict__ scales,
    const uint* __restrict__ part_edges,
    const int* __restrict__ counts,
    const float* __restrict__ Wself, const float* __restrict__ bself,
    const float* __restrict__ Wneigh, const float* __restrict__ bneigh,
    float* __restrict__ out)
{
    using short8 = __attribute__((ext_vector_type(8))) short;
    using f32x4  = __attribute__((ext_vector_type(4))) float;

    __shared__ u16   Axm[208 * 200];     // 83200 B
    __shared__ short Bb[96 * 200];       // 38400 B
    __shared__ uint  recs[CAP];          // 16384 B
    __shared__ u16   ssrc[CAP];          //  8192 B
    __shared__ int   bc[256];
    __shared__ int   csc[256];
    __shared__ int   hist[256];
    __shared__ int   cur[256];

    const int tid = threadIdx.x;
    const int p = blockIdx.x;
    const int node0 = p * PSZ;

    // ---- Bb from global (independent; overlaps sort setup) ----
    for (int idx = tid; idx < 96 * 96; idx += 1024) {
        int j = idx / 96;
        int k = idx - j * 96;
        Bb[j * 200 + k]      = (short)f2bf(Wself[idx]);
        Bb[j * 200 + 96 + k] = (short)f2bf(Wneigh[idx]);
    }

    // ---- counts row (coalesced) + init ----
    if (tid < 256) {
        int v = (tid < NBINBLK) ? counts[p * NBINBLK + tid] : 0;
        bc[tid] = v;
        csc[tid] = v;
        cur[tid] = 0;
    }

    // ---- stage x-half of Axm (bf16, full precision self term) ----
    for (int i = tid; i < PSZ * 12; i += 1024) {
        int n = i / 12, t = i - n * 12;
        int node = node0 + n;
        short8 v = (short8)0;
        if (node < N_NODES)
            v = *reinterpret_cast<const short8*>(xbf + (size_t)node * DIM + t * 8);
        *reinterpret_cast<short8*>(&Axm[n * 200 + t * 8]) = v;
    }
    __syncthreads();

    wave_scan256(csc, tid);
    __syncthreads();
    int m = csc[255]; if (m > CAP) m = CAP;

    // ---- compact cells -> recs ----
    for (int i = tid; i < NBINBLK * BINCAP; i += 1024) {
        int b = i / BINCAP;
        int s = i - b * BINCAP;
        if (s < bc[b]) {
            int dst = csc[b] - bc[b] + s;
            if (dst < CAP)
                recs[dst] = part_edges[(size_t)p * BPP + i];
        }
    }
    __syncthreads();

    // ---- node histogram + scan ----
    for (int i = tid; i < m; i += 1024)
        atomicAdd(&cur[recs[i] >> 16], 1);
    __syncthreads();
    if (tid < 256) hist[tid] = cur[tid];
    __syncthreads();
    wave_scan256(hist, tid);
    __syncthreads();
    if (tid < 256) cur[tid] = hist[tid] - cur[tid];   // exclusive cursor
    __syncthreads();

    // ---- scatter to node-sorted ssrc ----
    for (int i = tid; i < m; i += 1024) {
        uint r = recs[i];
        int pos = atomicAdd(&cur[r >> 16], 1);
        ssrc[pos] = (u16)(r & 0xFFFF);
    }
    __syncthreads();

    // ---- int8 gather + mean -> Axm[.. + 96]: 85 groups of 12 lanes, 8B/lane ----
    if (tid < 1020) {
        const int g = tid / 12;
        const int l = tid - g * 12;
        const int l8b = l * 8;                // byte offset in 96-B int8 row
        for (int r = g; r < PSZ; r += 85) {
            int end = hist[r];
            int beg = (r > 0) ? hist[r - 1] : 0;
            float a0 = 0.f, a1 = 0.f, a2 = 0.f, a3 = 0.f;
            float a4 = 0.f, a5 = 0.f, a6 = 0.f, a7 = 0.f;
            int i = beg;
            for (; i + 3 < end; i += 4) {
                int s0 = ssrc[i], s1 = ssrc[i + 1], s2 = ssrc[i + 2], s3 = ssrc[i + 3];
                QV q0, q1, q2, q3;
                q0.u = *reinterpret_cast<const uint2*>(xq + (size_t)s0 * DIM + l8b);
                q1.u = *reinterpret_cast<const uint2*>(xq + (size_t)s1 * DIM + l8b);
                q2.u = *reinterpret_cast<const uint2*>(xq + (size_t)s2 * DIM + l8b);
                q3.u = *reinterpret_cast<const uint2*>(xq + (size_t)s3 * DIM + l8b);
                float c0 = scales[s0], c1 = scales[s1], c2 = scales[s2], c3 = scales[s3];
                a0 += c0 * (float)q0.b[0] + c1 * (float)q1.b[0]
                    + c2 * (float)q2.b[0] + c3 * (float)q3.b[0];
                a1 += c0 * (float)q0.b[1] + c1 * (float)q1.b[1]
                    + c2 * (float)q2.b[1] + c3 * (float)q3.b[1];
                a2 += c0 * (float)q0.b[2] + c1 * (float)q1.b[2]
                    + c2 * (float)q2.b[2] + c3 * (float)q3.b[2];
                a3 += c0 * (float)q0.b[3] + c1 * (float)q1.b[3]
                    + c2 * (float)q2.b[3] + c3 * (float)q3.b[3];
                a4 += c0 * (float)q0.b[4] + c1 * (float)q1.b[4]
                    + c2 * (float)q2.b[4] + c3 * (float)q3.b[4];
                a5 += c0 * (float)q0.b[5] + c1 * (float)q1.b[5]
                    + c2 * (float)q2.b[5] + c3 * (float)q3.b[5];
                a6 += c0 * (float)q0.b[6] + c1 * (float)q1.b[6]
                    + c2 * (float)q2.b[6] + c3 * (float)q3.b[6];
                a7 += c0 * (float)q0.b[7] + c1 * (float)q1.b[7]
                    + c2 * (float)q2.b[7] + c3 * (float)q3.b[7];
            }
            for (; i < end; i++) {
                int s = ssrc[i];
                QV q;
                q.u = *reinterpret_cast<const uint2*>(xq + (size_t)s * DIM + l8b);
                float c = scales[s];
                a0 += c * (float)q.b[0]; a1 += c * (float)q.b[1];
                a2 += c * (float)q.b[2]; a3 += c * (float)q.b[3];
                a4 += c * (float)q.b[4]; a5 += c * (float)q.b[5];
                a6 += c * (float)q.b[6]; a7 += c * (float)q.b[7];
            }
            float inv = (end > beg) ? 1.0f / (float)(end - beg) : 0.f;
            ushort4 o0, o1;
            o0.x = f2bf(a0 * inv); o0.y = f2bf(a1 * inv);
            o0.z = f2bf(a2 * inv); o0.w = f2bf(a3 * inv);
            o1.x = f2bf(a4 * inv); o1.y = f2bf(a5 * inv);
            o1.z = f2bf(a6 * inv); o1.w = f2bf(a7 * inv);
            u16* ob = &Axm[r * 200 + 96 + l8b];
            *reinterpret_cast<ushort4*>(ob)     = o0;
            *reinterpret_cast<ushort4*>(ob + 4) = o1;
        }
    }
    __syncthreads();

    // ---- MFMA: 13 row-tiles of 16 over waves 0..12 ----
    const int wave = tid >> 6;
    const int lane = tid & 63;
    const int quad = lane >> 4;
    const int m16  = lane & 15;

    if (wave < 13) {
        const int rloc = wave * 16;
        f32x4 acc[6];
#pragma unroll
        for (int nt = 0; nt < 6; nt++) acc[nt] = (f32x4){0.f, 0.f, 0.f, 0.f};

#pragma unroll
        for (int kt = 0; kt < 6; kt++) {
            short8 a = *reinterpret_cast<const short8*>(
                &Axm[(rloc + m16) * 200 + kt * 32 + quad * 8]);
#pragma unroll
            for (int nt = 0; nt < 6; nt++) {
                short8 b = *reinterpret_cast<const short8*>(
                    &Bb[(nt * 16 + m16) * 200 + kt * 32 + quad * 8]);
                acc[nt] = __builtin_amdgcn_mfma_f32_16x16x32_bf16(a, b, acc[nt], 0, 0, 0);
            }
        }

#pragma unroll
        for (int nt = 0; nt < 6; nt++) {
            int col = nt * 16 + m16;
            float bias = bself[col] + bneigh[col];
#pragma unroll
            for (int reg = 0; reg < 4; reg++) {
                int rl = rloc + quad * 4 + reg;
                int row = node0 + rl;
                if (rl < PSZ && row < N_NODES)
                    out[(size_t)row * DIM + col] = acc[nt][reg] + bias;
            }
        }
    }
}

extern "C" void kernel_launch(void* const* d_in, const int* in_sizes, int n_in,
                              void* d_out, int out_size, void* d_ws, size_t ws_size,
                              hipStream_t stream) {
    const float* x      = (const float*)d_in[0];
    const int*   ei     = (const int*)d_in[1];
    const float* Wself  = (const float*)d_in[2];
    const float* bself  = (const float*)d_in[3];
    const float* Wneigh = (const float*)d_in[4];
    const float* bneigh = (const float*)d_in[5];
    float* out = (float*)d_out;

    // Workspace (fully written before read; no memset):
    uint* part_edges = (uint*)d_ws;                                  // 9,633,792 B
    int*  counts     = (int*)(part_edges + (size_t)NPART * BPP);     //   200,704 B
    u16*  xbf        = (u16*)(counts + NPART * NBINBLK);             // 9,600,000 B (16B-aligned)
    signed char* xq  = (signed char*)(xbf + (size_t)N_NODES * DIM);  // 4,800,000 B (8B-aligned)
    float* scales    = (float*)(xq + (size_t)N_NODES * DIM);         //   200,000 B

    packbin_k<<<NBINBLK + NROWBLK, 256, 0, stream>>>(
        x, ei, xbf, xq, scales, part_edges, counts);
    fused_k<<<NPART, 1024, 0, stream>>>(
        xbf, xq, scales, part_edges, counts, Wself, bself, Wneigh, bneigh, out);
}